// Round 1
// 672.865 us; speedup vs baseline: 1.1698x; 1.1698x over previous
//
#include <hip/hip_runtime.h>

// LlamaAttention: B=2, S=2048, HID=4096, NH=32, NKV=8, HD=128, GQA rep=4, RoPE, causal.
// Round 5: both bf16 GEMMs rewritten as deep-pipelined 8-wave kernels:
//   BK=32, 4-stage LDS ring, stages issued 3 K-tiles ahead, counted vmcnt
//   (never 0 in main loop), raw s_barrier (no compiler vmcnt(0) drain),
//   swizzled LDS (2-way max bank aliasing), setprio around MFMA cluster.
// qkv: 128x256 tiles -> 768 blocks = 3/CU exact. out: 256x256 -> 256 = 1/CU.
// cvt / rope / flash_attn / fallbacks unchanged.

typedef __bf16 bf16x8 __attribute__((ext_vector_type(8)));
typedef __bf16 bf16x4 __attribute__((ext_vector_type(4)));
typedef float floatx4 __attribute__((ext_vector_type(4)));

#define S_LEN 2048
#define HIDN  4096
#define NH    32
#define NKV   8
#define HD    128

__device__ inline void async_copy16(const void* g, void* l) {
  __builtin_amdgcn_global_load_lds(
      (const __attribute__((address_space(1))) void*)g,
      (__attribute__((address_space(3))) void*)l, 16, 0, 0);
}

template<int N> __device__ __forceinline__ void waitv() {
  static_assert(N == 0 || N == 3 || N == 4 || N == 6 || N == 8, "vmcnt");
  if constexpr (N == 0)      asm volatile("s_waitcnt vmcnt(0)" ::: "memory");
  else if constexpr (N == 3) asm volatile("s_waitcnt vmcnt(3)" ::: "memory");
  else if constexpr (N == 4) asm volatile("s_waitcnt vmcnt(4)" ::: "memory");
  else if constexpr (N == 6) asm volatile("s_waitcnt vmcnt(6)" ::: "memory");
  else                       asm volatile("s_waitcnt vmcnt(8)" ::: "memory");
}

// ---------------------------------------------------------------------------
// fp32 -> bf16 bulk convert: 8 elems/thread.
// ---------------------------------------------------------------------------
__global__ __launch_bounds__(256) void cvt_bf16(const float* __restrict__ src,
                                                __bf16* __restrict__ dst, int n8)
{
  int i = blockIdx.x * 256 + threadIdx.x;
  if (i >= n8) return;
  const float4* s = (const float4*)src + (size_t)i * 2;
  float4 a = s[0], b = s[1];
  bf16x8 r = {(__bf16)a.x, (__bf16)a.y, (__bf16)a.z, (__bf16)a.w,
              (__bf16)b.x, (__bf16)b.y, (__bf16)b.z, (__bf16)b.w};
  *((bf16x8*)dst + i) = r;
}

// ---------------------------------------------------------------------------
// Deep-pipelined NT GEMM core: C = A(MxK row-major) * WB(NxK row-major)^T.
// BN=256, BK=32, 512 threads = 8 waves (2M x 4N); per-wave tile (MI_REP*16)x64.
// LDS ring of 4 stages; stage for K-tile kt+3 issued at top of tile kt.
// Gate: s_waitcnt vmcnt(2*LPT) + s_barrier once per tile (counted, not 0).
// LDS swizzle: 16B slot index = quad ^ ((l16>>1)&3); global source is
// pre-swizzled so the linear global_load_lds write produces this layout
// (both-sides-or-neither). Wave ds_read_b128 -> 8 lanes per 16B slot,
// alternating bank halves per row parity => ~2-way aliasing (free, m136).
// Fragment conventions identical to the previously-verified kernel:
//   acc = mfma(b_frag, a_frag, acc);  C: m = ...+l16, n = ...+quad*4+reg.
// ---------------------------------------------------------------------------
template<int MI_REP>
__device__ __forceinline__ void gemm_core(
    const __bf16* __restrict__ A, const __bf16* __restrict__ WB,
    __bf16* lds, int m0, int n0, int tid, floatx4 (&acc)[MI_REP][4])
{
  constexpr int BM       = MI_REP * 32;       // 128 or 256
  constexpr int A_BYTES  = BM * 64;           // per-stage A bytes (32 cols bf16)
  constexpr int STAGE_B  = A_BYTES + 256 * 64;// per-stage total bytes
  constexpr int A_ROUNDS = BM / 128;          // 1 or 2 loads/thread for A
  constexpr int LPT      = A_ROUNDS + 2;      // loads per thread per tile
  constexpr int NK       = HIDN / 32;         // 128 K-tiles

  const int wave = tid >> 6, lane = tid & 63;
  const int quad = lane >> 4, l16 = lane & 15;
  const int wm = wave >> 2, wn = wave & 3;

  // Staging source (pre-swizzled): linear LDS slot idx -> row = idx>>2,
  // written slot c4 = idx&3 holds logical K-chunk qlog = (idx&3)^((idx>>3)&3).
  size_t a_src[A_ROUNDS], b_src[2];
  #pragma unroll
  for (int ra = 0; ra < A_ROUNDS; ra++) {
    int idx = ra * 512 + tid;
    int row = idx >> 2, qlog = (idx & 3) ^ ((idx >> 3) & 3);
    a_src[ra] = (size_t)(m0 + row) * HIDN + qlog * 8;
  }
  #pragma unroll
  for (int rb = 0; rb < 2; rb++) {
    int idx = rb * 512 + tid;
    int row = idx >> 2, qlog = (idx & 3) ^ ((idx >> 3) & 3);
    b_src[rb] = (size_t)(n0 + row) * HIDN + qlog * 8;
  }
  // ds_read lane offsets (bytes within a stage); reading slot
  // quad ^ ((row>>1)&3) retrieves logical K-chunk quad*8.
  const int sw   = (quad ^ ((l16 >> 1) & 3)) * 16;
  const int a_rd = (wm * (MI_REP * 16) + l16) * 64 + sw;
  const int b_rd = A_BYTES + (wn * 64 + l16) * 64 + sw;

  #pragma unroll
  for (int mi = 0; mi < MI_REP; mi++)
    #pragma unroll
    for (int ni = 0; ni < 4; ni++) acc[mi][ni] = (floatx4){0.f, 0.f, 0.f, 0.f};

  char* ldsb = (char*)lds;
  auto stage = [&](int kt) {
    char* sb = ldsb + (size_t)(kt & 3) * STAGE_B;
    const __bf16* ak = A  + (size_t)kt * 32;
    const __bf16* bk = WB + (size_t)kt * 32;
    #pragma unroll
    for (int ra = 0; ra < A_ROUNDS; ra++)
      async_copy16(ak + a_src[ra], sb + (ra * 512 + tid) * 16);
    #pragma unroll
    for (int rb = 0; rb < 2; rb++)
      async_copy16(bk + b_src[rb], sb + A_BYTES + (rb * 512 + tid) * 16);
  };

  // prologue: 3 tiles in flight
  stage(0); stage(1); stage(2);

  #pragma unroll 4
  for (int kt = 0; kt < NK; kt++) {
    // Gate: my loads for tile kt landed (allow tiles kt+1,kt+2 in flight);
    // barrier => everyone's landed AND everyone done reading tile kt-1's
    // region (which stage(kt+3) is about to overwrite).
    if (kt < NK - 2)       waitv<2 * LPT>();
    else if (kt == NK - 2) waitv<LPT>();
    else                   waitv<0>();
    __builtin_amdgcn_s_barrier();
    asm volatile("" ::: "memory");
    if (kt + 3 < NK) stage(kt + 3);

    const char* sb = ldsb + (size_t)(kt & 3) * STAGE_B;
    bf16x8 bv[4], av[MI_REP];
    #pragma unroll
    for (int ni = 0; ni < 4; ni++)
      bv[ni] = *(const bf16x8*)(sb + b_rd + ni * 1024);
    #pragma unroll
    for (int mi = 0; mi < MI_REP; mi++)
      av[mi] = *(const bf16x8*)(sb + a_rd + mi * 1024);

    __builtin_amdgcn_s_setprio(1);
    #pragma unroll
    for (int mi = 0; mi < MI_REP; mi++)
      #pragma unroll
      for (int ni = 0; ni < 4; ni++)
        acc[mi][ni] = __builtin_amdgcn_mfma_f32_16x16x32_bf16(
            bv[ni], av[mi], acc[mi][ni], 0, 0, 0);
    __builtin_amdgcn_s_setprio(0);
  }
}

// ---------------------------------------------------------------------------
// FAST QKV GEMM (bf16 in): 128x256 tiles, grid (24,32) = 768 blocks = 3/CU.
// ---------------------------------------------------------------------------
__global__ __launch_bounds__(512, 2) void qkv_gemm_bf16(
    const __bf16* __restrict__ A, const __bf16* __restrict__ WB,
    __bf16* __restrict__ Qb, __bf16* __restrict__ Kb, __bf16* __restrict__ Vt)
{
  __shared__ __bf16 lds[4 * (128 + 256) * 32];   // 96 KB
  const int tid = threadIdx.x;
  const int m0 = blockIdx.y * 128, n0 = blockIdx.x * 256;
  floatx4 acc[4][4];
  gemm_core<4>(A, WB, lds, m0, n0, tid, acc);

  const int wave = tid >> 6, lane = tid & 63;
  const int quad = lane >> 4, l16 = lane & 15;
  const int wm = wave >> 2, wn = wave & 3;
  #pragma unroll
  for (int mi = 0; mi < 4; mi++) {
    int m = m0 + wm * 64 + mi * 16 + l16;
    int b = m >> 11, s = m & (S_LEN - 1);
    #pragma unroll
    for (int ni = 0; ni < 4; ni++) {
      int nb = n0 + wn * 64 + ni * 16 + quad * 4;
      if (nb < 4096) {
        int hh = nb >> 7, d = nb & 127;
        bf16x4 v = {(__bf16)acc[mi][ni][0], (__bf16)acc[mi][ni][1],
                    (__bf16)acc[mi][ni][2], (__bf16)acc[mi][ni][3]};
        *(bf16x4*)&Qb[(((size_t)b * NH + hh) * S_LEN + s) * HD + d] = v;
      } else if (nb < 5120) {
        int nl = nb - 4096, hh = nl >> 7, d = nl & 127;
        bf16x4 v = {(__bf16)acc[mi][ni][0], (__bf16)acc[mi][ni][1],
                    (__bf16)acc[mi][ni][2], (__bf16)acc[mi][ni][3]};
        *(bf16x4*)&Kb[(((size_t)b * NKV + hh) * S_LEN + s) * HD + d] = v;
      } else {
        int nl = nb - 5120, hh = nl >> 7, d = nl & 127;
        #pragma unroll
        for (int r = 0; r < 4; r++)
          Vt[(((size_t)b * NKV + hh) * HD + d + r) * S_LEN + s] =
              (__bf16)acc[mi][ni][r];
      }
    }
  }
}

// ---------------------------------------------------------------------------
// FAST OUT GEMM (bf16 in, fp32 out): 256x256 tiles, grid (16,16) = 1/CU exact.
// ---------------------------------------------------------------------------
__global__ __launch_bounds__(512, 2) void out_gemm_bf16(
    const __bf16* __restrict__ A, const __bf16* __restrict__ WB,
    float* __restrict__ C)
{
  __shared__ __bf16 lds[4 * (256 + 256) * 32];   // 128 KB
  const int tid = threadIdx.x;
  const int m0 = blockIdx.y * 256, n0 = blockIdx.x * 256;
  floatx4 acc[8][4];
  gemm_core<8>(A, WB, lds, m0, n0, tid, acc);

  const int wave = tid >> 6, lane = tid & 63;
  const int quad = lane >> 4, l16 = lane & 15;
  const int wm = wave >> 2, wn = wave & 3;
  #pragma unroll
  for (int mi = 0; mi < 8; mi++) {
    int m = m0 + wm * 128 + mi * 16 + l16;
    #pragma unroll
    for (int ni = 0; ni < 4; ni++) {
      int nb = n0 + wn * 64 + ni * 16 + quad * 4;
      *(floatx4*)&C[(size_t)m * HIDN + nb] = acc[mi][ni];
    }
  }
}

// ---------------------------------------------------------------------------
// FALLBACK QKV GEMM (fp32 in) — round-1 version.
// ---------------------------------------------------------------------------
__global__ __launch_bounds__(256) void qkv_gemm_f32(
    const float* __restrict__ A, const float* __restrict__ Wq,
    const float* __restrict__ Wk, const float* __restrict__ Wv,
    __bf16* __restrict__ Qb, __bf16* __restrict__ Kb, __bf16* __restrict__ Vt)
{
  __shared__ __bf16 As[128 * 40];
  __shared__ __bf16 Bs[128 * 40];
  const int tid  = threadIdx.x;
  const int wave = tid >> 6, lane = tid & 63;
  const int quad = lane >> 4, l16 = lane & 15;
  const int wrow = (wave >> 1) * 64, wcol = (wave & 1) * 64;
  const int m0 = blockIdx.y * 128;
  const int n0 = blockIdx.x * 128;

  const float* W; int wr0; int sel;
  if (n0 < 4096)      { W = Wq; wr0 = n0;        sel = 0; }
  else if (n0 < 5120) { W = Wk; wr0 = n0 - 4096; sel = 1; }
  else                { W = Wv; wr0 = n0 - 5120; sel = 2; }

  floatx4 acc[4][4];
  #pragma unroll
  for (int i = 0; i < 4; i++)
    #pragma unroll
    for (int j = 0; j < 4; j++) acc[i][j] = (floatx4){0.f, 0.f, 0.f, 0.f};

  for (int k0 = 0; k0 < HIDN; k0 += 32) {
    __syncthreads();
    #pragma unroll
    for (int it = 0; it < 4; ++it) {
      int c = tid + it * 256;
      int row = c >> 3, c4 = (c & 7) * 4;
      float4 va = *(const float4*)(A + (size_t)(m0 + row) * HIDN + k0 + c4);
      __bf16* da = &As[row * 40 + c4];
      da[0] = (__bf16)va.x; da[1] = (__bf16)va.y; da[2] = (__bf16)va.z; da[3] = (__bf16)va.w;
      float4 vb = *(const float4*)(W + (size_t)(wr0 + row) * HIDN + k0 + c4);
      __bf16* db = &Bs[row * 40 + c4];
      db[0] = (__bf16)vb.x; db[1] = (__bf16)vb.y; db[2] = (__bf16)vb.z; db[3] = (__bf16)vb.w;
    }
    __syncthreads();
    bf16x8 af[4], bfr[4];
    #pragma unroll
    for (int i = 0; i < 4; i++)
      af[i] = *(const bf16x8*)&As[(wrow + i * 16 + l16) * 40 + quad * 8];
    #pragma unroll
    for (int j = 0; j < 4; j++)
      bfr[j] = *(const bf16x8*)&Bs[(wcol + j * 16 + l16) * 40 + quad * 8];
    #pragma unroll
    for (int i = 0; i < 4; i++)
      #pragma unroll
      for (int j = 0; j < 4; j++)
        acc[i][j] = __builtin_amdgcn_mfma_f32_16x16x32_bf16(af[i], bfr[j], acc[i][j], 0, 0, 0);
  }

  #pragma unroll
  for (int i = 0; i < 4; i++) {
    #pragma unroll
    for (int j = 0; j < 4; j++) {
      #pragma unroll
      for (int r = 0; r < 4; r++) {
        int m = m0 + wrow + i * 16 + quad * 4 + r;
        int n = n0 + wcol + j * 16 + l16;
        __bf16 v = (__bf16)acc[i][j][r];
        int b = m >> 11, s = m & (S_LEN - 1);
        if (sel == 0) {
          int h = n >> 7, d = n & 127;
          Qb[(((size_t)b * NH + h) * S_LEN + s) * HD + d] = v;
        } else if (sel == 1) {
          int nl = n - 4096, h = nl >> 7, d = nl & 127;
          Kb[(((size_t)b * NKV + h) * S_LEN + s) * HD + d] = v;
        } else {
          int nl = n - 5120, h = nl >> 7, d = nl & 127;
          Vt[(((size_t)b * NKV + h) * HD + d) * S_LEN + s] = v;
        }
      }
    }
  }
}

// ---------------------------------------------------------------------------
// FALLBACK OUT GEMM (fp32 Wo) — round-1 version.
// ---------------------------------------------------------------------------
__global__ __launch_bounds__(256) void out_gemm_f32(
    const __bf16* __restrict__ A, const float* __restrict__ Wo,
    float* __restrict__ C)
{
  __shared__ __bf16 As[128 * 40];
  __shared__ __bf16 Bs[128 * 40];
  const int tid  = threadIdx.x;
  const int wave = tid >> 6, lane = tid & 63;
  const int quad = lane >> 4, l16 = lane & 15;
  const int wrow = (wave >> 1) * 64, wcol = (wave & 1) * 64;
  const int m0 = blockIdx.y * 128;
  const int n0 = blockIdx.x * 128;

  floatx4 acc[4][4];
  #pragma unroll
  for (int i = 0; i < 4; i++)
    #pragma unroll
    for (int j = 0; j < 4; j++) acc[i][j] = (floatx4){0.f, 0.f, 0.f, 0.f};

  for (int k0 = 0; k0 < HIDN; k0 += 32) {
    __syncthreads();
    #pragma unroll
    for (int it = 0; it < 2; ++it) {
      int c = tid + it * 256;
      int row = c >> 2, c8 = (c & 3) * 8;
      *(bf16x8*)&As[row * 40 + c8] =
          *(const bf16x8*)(A + (size_t)(m0 + row) * HIDN + k0 + c8);
    }
    #pragma unroll
    for (int it = 0; it < 4; ++it) {
      int c = tid + it * 256;
      int row = c >> 3, c4 = (c & 7) * 4;
      float4 vb = *(const float4*)(Wo + (size_t)(n0 + row) * HIDN + k0 + c4);
      __bf16* db = &Bs[row * 40 + c4];
      db[0] = (__bf16)vb.x; db[1] = (__bf16)vb.y; db[2] = (__bf16)vb.z; db[3] = (__bf16)vb.w;
    }
    __syncthreads();
    bf16x8 af[4], bfr[4];
    #pragma unroll
    for (int i = 0; i < 4; i++)
      af[i] = *(const bf16x8*)&As[(wrow + i * 16 + l16) * 40 + quad * 8];
    #pragma unroll
    for (int j = 0; j < 4; j++)
      bfr[j] = *(const bf16x8*)&Bs[(wcol + j * 16 + l16) * 40 + quad * 8];
    #pragma unroll
    for (int i = 0; i < 4; i++)
      #pragma unroll
      for (int j = 0; j < 4; j++)
        acc[i][j] = __builtin_amdgcn_mfma_f32_16x16x32_bf16(af[i], bfr[j], acc[i][j], 0, 0, 0);
  }

  #pragma unroll
  for (int i = 0; i < 4; i++)
    #pragma unroll
    for (int j = 0; j < 4; j++)
      #pragma unroll
      for (int r = 0; r < 4; r++) {
        int m = m0 + wrow + i * 16 + quad * 4 + r;
        int n = n0 + wcol + j * 16 + l16;
        C[(size_t)m * HIDN + n] = acc[i][j][r];
      }
}

// ---------------------------------------------------------------------------
// RoPE in-place on bf16 Q and K.
// ---------------------------------------------------------------------------
__global__ __launch_bounds__(256) void rope_kernel(
    __bf16* __restrict__ Qb, __bf16* __restrict__ Kb,
    const float* __restrict__ cosp, const float* __restrict__ sinp)
{
  size_t i = (size_t)blockIdx.x * 256 + threadIdx.x;
  const size_t QP = (size_t)2 * NH * S_LEN * 64;
  __bf16* buf; int H; size_t t;
  if (i < QP) { buf = Qb; H = NH;  t = i; }
  else        { buf = Kb; H = NKV; t = i - QP; }
  int d = (int)(t & 63);
  int s = (int)((t >> 6) & (S_LEN - 1));
  size_t rest = t >> 17;
  int h = (int)(rest % H);
  int b = (int)(rest / H);
  size_t base = (((size_t)b * H + h) * S_LEN + s) * HD;
  float q0 = (float)buf[base + d];
  float q1 = (float)buf[base + d + 64];
  float c  = cosp[((size_t)b * S_LEN + s) * HD + d];
  float sn = sinp[((size_t)b * S_LEN + s) * HD + d];
  buf[base + d]      = (__bf16)(q0 * c - q1 * sn);
  buf[base + d + 64] = (__bf16)(q1 * c + q0 * sn);
}

// ---------------------------------------------------------------------------
// Flash attention, causal, GQA. (unchanged from round 4)
// ---------------------------------------------------------------------------
__global__ __launch_bounds__(256, 2) void flash_attn(
    const __bf16* __restrict__ Q, const __bf16* __restrict__ Kc,
    const __bf16* __restrict__ Vt, __bf16* __restrict__ Out)
{
  __shared__ __bf16 Ks[64 * 136];
  __shared__ __bf16 VTs[128 * 72];
  __shared__ __bf16 Ps[4 * 32 * 72];
  const int tid  = threadIdx.x;
  const int wave = tid >> 6, lane = tid & 63;
  const int quad = lane >> 4, l16 = lane & 15;
  const int bh = blockIdx.x;
  const int h = bh & 31, b = bh >> 5;
  const int qt = 15 - (int)blockIdx.y;   // longest first
  const int kvh = h >> 2;
  const size_t qbase  = (((size_t)b * NH + h) * S_LEN + qt * 128 + wave * 32) * HD;
  const size_t kbase  = ((size_t)b * NKV + kvh) * S_LEN * HD;
  const size_t vtbase = ((size_t)b * NKV + kvh) * (size_t)HD * S_LEN;
  const int psbase = wave * (32 * 72);

  bf16x8 qf[2][4];
  #pragma unroll
  for (int st = 0; st < 2; st++)
    #pragma unroll
    for (int kk = 0; kk < 4; kk++)
      qf[st][kk] = *(const bf16x8*)&Q[qbase + (size_t)(st * 16 + l16) * HD + kk * 32 + quad * 8];

  floatx4 o[2][8];
  floatx4 ol[2];
  #pragma unroll
  for (int st = 0; st < 2; st++) {
    ol[st] = (floatx4){0.f, 0.f, 0.f, 0.f};
    #pragma unroll
    for (int ct = 0; ct < 8; ct++) o[st][ct] = (floatx4){0.f, 0.f, 0.f, 0.f};
  }
  bf16x8 onesv;
  #pragma unroll
  for (int u = 0; u < 8; u++) onesv[u] = (__bf16)1.0f;

  const float c1 = 0.12753785f;   // scale * log2(e) = 128^-0.5 * 1.4426950
  const float c2 = -28.853900f;   // -20 * log2(e)
  const int kj_end = 2 * qt + 2;

  // prologue prefetch for kj = 0
  bf16x8 kreg[4], vreg[4];
  #pragma unroll
  for (int it = 0; it < 4; ++it) {
    int c = tid + it * 256;
    kreg[it] = *(const bf16x8*)&Kc[kbase + (size_t)((c >> 4)) * HD + (c & 15) * 8];
    vreg[it] = *(const bf16x8*)&Vt[vtbase + (size_t)(c >> 3) * S_LEN + (c & 7) * 8];
  }

  for (int kj = 0; kj < kj_end; ++kj) {
    __syncthreads();  // B1: prev iter's LDS reads done
    #pragma unroll
    for (int it = 0; it < 4; ++it) {
      int c = tid + it * 256;
      *(bf16x8*)&Ks[(c >> 4) * 136 + (c & 15) * 8] = kreg[it];
      *(bf16x8*)&VTs[(c >> 3) * 72 + (c & 7) * 8] = vreg[it];
    }
    __syncthreads();  // B2: staging visible

    // issue next-iter loads NOW — they fly under the whole compute phase
    if (kj + 1 < kj_end) {
      #pragma unroll
      for (int it = 0; it < 4; ++it) {
        int c = tid + it * 256;
        kreg[it] = *(const bf16x8*)&Kc[kbase + (size_t)((kj + 1) * 64 + (c >> 4)) * HD + (c & 15) * 8];
        vreg[it] = *(const bf16x8*)&Vt[vtbase + (size_t)(c >> 3) * S_LEN + (kj + 1) * 64 + (c & 7) * 8];
      }
    }

    // scores, transposed: S^T[kv][q]; A = K rows, B = Q rows.
    floatx4 s[2][4];
    #pragma unroll
    for (int st = 0; st < 2; st++)
      #pragma unroll
      for (int j = 0; j < 4; j++) s[st][j] = (floatx4){0.f, 0.f, 0.f, 0.f};
    #pragma unroll
    for (int kk = 0; kk < 4; kk++) {
      bf16x8 ak[4];
      #pragma unroll
      for (int j = 0; j < 4; j++)
        ak[j] = *(const bf16x8*)&Ks[(j * 16 + l16) * 136 + kk * 32 + quad * 8];
      #pragma unroll
      for (int st = 0; st < 2; st++)
        #pragma unroll
        for (int j = 0; j < 4; j++)
          s[st][j] = __builtin_amdgcn_mfma_f32_16x16x32_bf16(ak[j], qf[st][kk], s[st][j], 0, 0, 0);
    }

    // p = exp2(s*c1 + c2), causal-masked to 0; write per-wave Ps (no barrier).
    #pragma unroll
    for (int st = 0; st < 2; st++) {
      const int qrow = qt * 128 + wave * 32 + st * 16 + l16;
      #pragma unroll
      for (int j = 0; j < 4; j++) {
        const int kvb = kj * 64 + j * 16 + quad * 4;
        bf16x4 pw;
        #pragma unroll
        for (int r = 0; r < 4; r++) {
          float p = __builtin_amdgcn_exp2f(fmaf(s[st][j][r], c1, c2));
          if (kvb + r > qrow) p = 0.0f;
          pw[r] = (__bf16)p;
        }
        *(bf16x4*)&Ps[psbase + (st * 16 + l16) * 72 + j * 16 + quad * 4] = pw;
      }
    }

    // PV + row-sum l: O(32x128) += P(32x64) * V(64x128); l += P * ones
    #pragma unroll
    for (int kk = 0; kk < 2; kk++) {
      bf16x8 bv[8];
      #pragma unroll
      for (int ct = 0; ct < 8; ct++)
        bv[ct] = *(const bf16x8*)&VTs[(ct * 16 + l16) * 72 + kk * 32 + quad * 8];
      #pragma unroll
      for (int st = 0; st < 2; st++) {
        bf16x8 ap = *(const bf16x8*)&Ps[psbase + (st * 16 + l16) * 72 + kk * 32 + quad * 8];
        ol[st] = __builtin_amdgcn_mfma_f32_16x16x32_bf16(ap, onesv, ol[st], 0, 0, 0);
        #pragma unroll
        for (int ct = 0; ct < 8; ct++)
          o[st][ct] = __builtin_amdgcn_mfma_f32_16x16x32_bf16(ap, bv[ct], o[st][ct], 0, 0, 0);
      }
    }
  }

  // epilogue: attn_out[b][s][h*128+d]; l = ol[st][r] (all cols identical)
  #pragma unroll
  for (int st = 0; st < 2; st++) {
    #pragma unroll
    for (int r = 0; r < 4; r++) {
      float rl = 1.0f / ol[st][r];
      int qi = qt * 128 + wave * 32 + st * 16 + quad * 4 + r;
      #pragma unroll
      for (int ct = 0; ct < 8; ct++) {
        Out[((size_t)b * S_LEN + qi) * HIDN + h * HD + ct * 16 + l16] =
            (__bf16)(o[st][ct][r] * rl);
      }
    }
  }
}

// ---------------------------------------------------------------------------
extern "C" void kernel_launch(void* const* d_in, const int* in_sizes, int n_in,
                              void* d_out, int out_size, void* d_ws, size_t ws_size,
                              hipStream_t stream)
{
  const float* hs   = (const float*)d_in[0];
  const float* cosp = (const float*)d_in[1];
  const float* sinp = (const float*)d_in[2];
  // d_in[3] = attention_mask: exactly causal -1e9, applied analytically in flash_attn
  const float* Wq   = (const float*)d_in[4];
  const float* Wk   = (const float*)d_in[5];
  const float* Wv   = (const float*)d_in[6];
  const float* Wo   = (const float*)d_in[7];
  float* out = (float*)d_out;

  __bf16* Qb  = (__bf16*)d_ws;                         // 16,777,216
  __bf16* Kb  = Qb  + (size_t)16777216;                //  4,194,304
  __bf16* Vtb = Kb  + (size_t)4194304;                 //  4,194,304

  if (ws_size >= (size_t)134217728) {
    __bf16* HSB = Vtb + (size_t)4194304;   // hs bf16; aliased by AO after qkv
    __bf16* AO  = HSB;
    __bf16* WB  = HSB + (size_t)16777216;  // Wq|Wk|Wv bf16; Wo aliases after qkv

    cvt_bf16<<<8192, 256, 0, stream>>>(hs, HSB, 2097152);
    cvt_bf16<<<8192, 256, 0, stream>>>(Wq, WB, 2097152);
    cvt_bf16<<<2048, 256, 0, stream>>>(Wk, WB + 16777216, 524288);
    cvt_bf16<<<2048, 256, 0, stream>>>(Wv, WB + 20971520, 524288);
    qkv_gemm_bf16<<<dim3(24, 32), 512, 0, stream>>>(HSB, WB, Qb, Kb, Vtb);
    cvt_bf16<<<8192, 256, 0, stream>>>(Wo, WB, 2097152);  // Wqkv dead now
    rope_kernel<<<40960, 256, 0, stream>>>(Qb, Kb, cosp, sinp);
    flash_attn<<<dim3(64, 16), 256, 0, stream>>>(Qb, Kb, Vtb, AO);
    out_gemm_bf16<<<dim3(16, 16), 512, 0, stream>>>(AO, WB, out);
  } else {
    __bf16* AO = Vtb + (size_t)4194304;
    qkv_gemm_f32<<<dim3(48, 32), 256, 0, stream>>>(hs, Wq, Wk, Wv, Qb, Kb, Vtb);
    rope_kernel<<<40960, 256, 0, stream>>>(Qb, Kb, cosp, sinp);
    flash_attn<<<dim3(64, 16), 256, 0, stream>>>(Qb, Kb, Vtb, AO);
    out_gemm_f32<<<dim3(32, 32), 256, 0, stream>>>(AO, Wo, out);
  }
}

// Round 2
// 655.156 us; speedup vs baseline: 1.2014x; 1.0270x over previous
//
#include <hip/hip_runtime.h>

// LlamaAttention: B=2, S=2048, HID=4096, NH=32, NKV=8, HD=128, GQA rep=4, RoPE, causal.
// Round 6: GEMM core BK 32->64 (per-tile fixed cost amortized over 2x MFMA),
//   3-stage 144KB LDS ring, 8-slot XOR swizzle, vmcnt(6) gate (counted).
//   Both GEMMs share BM=128/BN=256 core: qkv grid (24,32)=3/CU, out (16,32)=2/CU.
//   flash_attn: + s_setprio around MFMA clusters (T5).
// cvt / rope / fallbacks unchanged.

typedef __bf16 bf16x8 __attribute__((ext_vector_type(8)));
typedef __bf16 bf16x4 __attribute__((ext_vector_type(4)));
typedef float floatx4 __attribute__((ext_vector_type(4)));

#define S_LEN 2048
#define HIDN  4096
#define NH    32
#define NKV   8
#define HD    128

__device__ inline void async_copy16(const void* g, void* l) {
  __builtin_amdgcn_global_load_lds(
      (const __attribute__((address_space(1))) void*)g,
      (__attribute__((address_space(3))) void*)l, 16, 0, 0);
}

template<int N> __device__ __forceinline__ void waitv() {
  static_assert(N == 0 || N == 6, "vmcnt");
  if constexpr (N == 0) asm volatile("s_waitcnt vmcnt(0)" ::: "memory");
  else                  asm volatile("s_waitcnt vmcnt(6)" ::: "memory");
}

// ---------------------------------------------------------------------------
// fp32 -> bf16 bulk convert: 8 elems/thread.
// ---------------------------------------------------------------------------
__global__ __launch_bounds__(256) void cvt_bf16(const float* __restrict__ src,
                                                __bf16* __restrict__ dst, int n8)
{
  int i = blockIdx.x * 256 + threadIdx.x;
  if (i >= n8) return;
  const float4* s = (const float4*)src + (size_t)i * 2;
  float4 a = s[0], b = s[1];
  bf16x8 r = {(__bf16)a.x, (__bf16)a.y, (__bf16)a.z, (__bf16)a.w,
              (__bf16)b.x, (__bf16)b.y, (__bf16)b.z, (__bf16)b.w};
  *((bf16x8*)dst + i) = r;
}

// ---------------------------------------------------------------------------
// Deep-pipelined NT GEMM core: C = A(MxK rm) * WB(NxK rm)^T.
// BM=128, BN=256, BK=64; 512 threads = 8 waves (2M x 4N); per-wave 64x64.
// 3-stage LDS ring (48KB/stage = 144KB); stage(kt+2) issued at top of kt.
// Gate: vmcnt(6)+s_barrier once per tile (counted, never 0 in main loop).
// Overwrite safety: stage(kt+2) targets tile kt-1's slot; barrier at top of
// kt guarantees every wave's kt-1 ds_reads completed before arrival.
// 8-slot XOR swizzle (row stride 128B): LDS slot s of row r holds global
// chunk s^(r&7); global source pre-swizzled so the linear global_load_lds
// destination stays contiguous (both-sides-or-neither, rule 21).
// ds_read of chunk kk*4+quad = row*128 + 16*(quad^(l16&3)) +
// ((kk<<6)^(64*((l16>>2)&1))) — all compile-time imm offsets.
// MFMA convention identical to verified rounds: acc=mfma(b_frag,a_frag,acc);
// C: m = ...+l16, n = ...+quad*4+reg.
// ---------------------------------------------------------------------------
__device__ __forceinline__ void gemm_core64(
    const __bf16* __restrict__ A, const __bf16* __restrict__ WB,
    __bf16* lds, int m0, int n0, int tid, floatx4 (&acc)[4][4])
{
  constexpr int A_BYTES = 128 * 64 * 2;           // 16384
  constexpr int STAGE_B = (128 + 256) * 64 * 2;   // 49152
  constexpr int NK      = HIDN / 64;              // 64

  const int wave = tid >> 6, lane = tid & 63;
  const int quad = lane >> 4, l16 = lane & 15;
  const int wm = wave >> 2, wn = wave & 3;

  size_t a_src[2], b_src[4];
  #pragma unroll
  for (int ra = 0; ra < 2; ra++) {
    int idx = ra * 512 + tid;
    int row = idx >> 3, chunk = (idx & 7) ^ (row & 7);
    a_src[ra] = (size_t)(m0 + row) * HIDN + chunk * 8;
  }
  #pragma unroll
  for (int rb = 0; rb < 4; rb++) {
    int idx = rb * 512 + tid;
    int row = idx >> 3, chunk = (idx & 7) ^ (row & 7);
    b_src[rb] = (size_t)(n0 + row) * HIDN + chunk * 8;
  }

  const int swq  = (quad ^ (l16 & 3)) * 16;
  const int kxor = ((l16 >> 2) & 1) * 64;
  const int a_rd = (wm * 64 + l16) * 128 + swq;
  const int b_rd = A_BYTES + (wn * 64 + l16) * 128 + swq;

  #pragma unroll
  for (int mi = 0; mi < 4; mi++)
    #pragma unroll
    for (int ni = 0; ni < 4; ni++) acc[mi][ni] = (floatx4){0.f, 0.f, 0.f, 0.f};

  char* ldsb = (char*)lds;
  auto stage = [&](int kt, int slotB) {
    char* sb = ldsb + slotB;
    const size_t ko = (size_t)kt * 64;
    #pragma unroll
    for (int ra = 0; ra < 2; ra++)
      async_copy16(A + ko + a_src[ra], sb + (ra * 512 + tid) * 16);
    #pragma unroll
    for (int rb = 0; rb < 4; rb++)
      async_copy16(WB + ko + b_src[rb], sb + A_BYTES + (rb * 512 + tid) * 16);
  };

  stage(0, 0);
  stage(1, STAGE_B);

  int sco = 0, spo = 2 * STAGE_B;
  for (int kt = 0; kt < NK; kt++) {
    if (kt < NK - 1) waitv<6>();
    else             waitv<0>();
    __builtin_amdgcn_s_barrier();
    asm volatile("" ::: "memory");
    if (kt + 2 < NK) stage(kt + 2, spo);

    const char* sb = ldsb + sco;
    bf16x8 av[4][2], bv[4][2];
    #pragma unroll
    for (int kk = 0; kk < 2; kk++) {
      const int kb = (kk << 6) ^ kxor;
      #pragma unroll
      for (int ni = 0; ni < 4; ni++)
        bv[ni][kk] = *(const bf16x8*)(sb + b_rd + ni * 2048 + kb);
      #pragma unroll
      for (int mi = 0; mi < 4; mi++)
        av[mi][kk] = *(const bf16x8*)(sb + a_rd + mi * 2048 + kb);
    }
    __builtin_amdgcn_s_setprio(1);
    #pragma unroll
    for (int kk = 0; kk < 2; kk++)
      #pragma unroll
      for (int mi = 0; mi < 4; mi++)
        #pragma unroll
        for (int ni = 0; ni < 4; ni++)
          acc[mi][ni] = __builtin_amdgcn_mfma_f32_16x16x32_bf16(
              bv[ni][kk], av[mi][kk], acc[mi][ni], 0, 0, 0);
    __builtin_amdgcn_s_setprio(0);

    sco += STAGE_B; if (sco == 3 * STAGE_B) sco = 0;
    spo += STAGE_B; if (spo == 3 * STAGE_B) spo = 0;
  }
}

// ---------------------------------------------------------------------------
// FAST QKV GEMM (bf16 in): 128x256 tiles, grid (24,32) = 768 blocks = 3/CU.
// ---------------------------------------------------------------------------
__global__ __launch_bounds__(512, 2) void qkv_gemm_bf16(
    const __bf16* __restrict__ A, const __bf16* __restrict__ WB,
    __bf16* __restrict__ Qb, __bf16* __restrict__ Kb, __bf16* __restrict__ Vt)
{
  __shared__ __bf16 lds[3 * (128 + 256) * 32 * 2];   // 144 KB
  const int tid = threadIdx.x;
  const int m0 = blockIdx.y * 128, n0 = blockIdx.x * 256;
  floatx4 acc[4][4];
  gemm_core64(A, WB, lds, m0, n0, tid, acc);

  const int wave = tid >> 6, lane = tid & 63;
  const int quad = lane >> 4, l16 = lane & 15;
  const int wm = wave >> 2, wn = wave & 3;
  #pragma unroll
  for (int mi = 0; mi < 4; mi++) {
    int m = m0 + wm * 64 + mi * 16 + l16;
    int b = m >> 11, s = m & (S_LEN - 1);
    #pragma unroll
    for (int ni = 0; ni < 4; ni++) {
      int nb = n0 + wn * 64 + ni * 16 + quad * 4;
      if (nb < 4096) {
        int hh = nb >> 7, d = nb & 127;
        bf16x4 v = {(__bf16)acc[mi][ni][0], (__bf16)acc[mi][ni][1],
                    (__bf16)acc[mi][ni][2], (__bf16)acc[mi][ni][3]};
        *(bf16x4*)&Qb[(((size_t)b * NH + hh) * S_LEN + s) * HD + d] = v;
      } else if (nb < 5120) {
        int nl = nb - 4096, hh = nl >> 7, d = nl & 127;
        bf16x4 v = {(__bf16)acc[mi][ni][0], (__bf16)acc[mi][ni][1],
                    (__bf16)acc[mi][ni][2], (__bf16)acc[mi][ni][3]};
        *(bf16x4*)&Kb[(((size_t)b * NKV + hh) * S_LEN + s) * HD + d] = v;
      } else {
        int nl = nb - 5120, hh = nl >> 7, d = nl & 127;
        #pragma unroll
        for (int r = 0; r < 4; r++)
          Vt[(((size_t)b * NKV + hh) * HD + d + r) * S_LEN + s] =
              (__bf16)acc[mi][ni][r];
      }
    }
  }
}

// ---------------------------------------------------------------------------
// FAST OUT GEMM (bf16 in, fp32 out): 128x256 tiles, grid (16,32) = 2/CU exact.
// ---------------------------------------------------------------------------
__global__ __launch_bounds__(512, 2) void out_gemm_bf16(
    const __bf16* __restrict__ A, const __bf16* __restrict__ WB,
    float* __restrict__ C)
{
  __shared__ __bf16 lds[3 * (128 + 256) * 32 * 2];   // 144 KB
  const int tid = threadIdx.x;
  const int m0 = blockIdx.y * 128, n0 = blockIdx.x * 256;
  floatx4 acc[4][4];
  gemm_core64(A, WB, lds, m0, n0, tid, acc);

  const int wave = tid >> 6, lane = tid & 63;
  const int quad = lane >> 4, l16 = lane & 15;
  const int wm = wave >> 2, wn = wave & 3;
  #pragma unroll
  for (int mi = 0; mi < 4; mi++) {
    int m = m0 + wm * 64 + mi * 16 + l16;
    #pragma unroll
    for (int ni = 0; ni < 4; ni++) {
      int nb = n0 + wn * 64 + ni * 16 + quad * 4;
      *(floatx4*)&C[(size_t)m * HIDN + nb] = acc[mi][ni];
    }
  }
}

// ---------------------------------------------------------------------------
// FALLBACK QKV GEMM (fp32 in) — round-1 version.
// ---------------------------------------------------------------------------
__global__ __launch_bounds__(256) void qkv_gemm_f32(
    const float* __restrict__ A, const float* __restrict__ Wq,
    const float* __restrict__ Wk, const float* __restrict__ Wv,
    __bf16* __restrict__ Qb, __bf16* __restrict__ Kb, __bf16* __restrict__ Vt)
{
  __shared__ __bf16 As[128 * 40];
  __shared__ __bf16 Bs[128 * 40];
  const int tid  = threadIdx.x;
  const int wave = tid >> 6, lane = tid & 63;
  const int quad = lane >> 4, l16 = lane & 15;
  const int wrow = (wave >> 1) * 64, wcol = (wave & 1) * 64;
  const int m0 = blockIdx.y * 128;
  const int n0 = blockIdx.x * 128;

  const float* W; int wr0; int sel;
  if (n0 < 4096)      { W = Wq; wr0 = n0;        sel = 0; }
  else if (n0 < 5120) { W = Wk; wr0 = n0 - 4096; sel = 1; }
  else                { W = Wv; wr0 = n0 - 5120; sel = 2; }

  floatx4 acc[4][4];
  #pragma unroll
  for (int i = 0; i < 4; i++)
    #pragma unroll
    for (int j = 0; j < 4; j++) acc[i][j] = (floatx4){0.f, 0.f, 0.f, 0.f};

  for (int k0 = 0; k0 < HIDN; k0 += 32) {
    __syncthreads();
    #pragma unroll
    for (int it = 0; it < 4; ++it) {
      int c = tid + it * 256;
      int row = c >> 3, c4 = (c & 7) * 4;
      float4 va = *(const float4*)(A + (size_t)(m0 + row) * HIDN + k0 + c4);
      __bf16* da = &As[row * 40 + c4];
      da[0] = (__bf16)va.x; da[1] = (__bf16)va.y; da[2] = (__bf16)va.z; da[3] = (__bf16)va.w;
      float4 vb = *(const float4*)(W + (size_t)(wr0 + row) * HIDN + k0 + c4);
      __bf16* db = &Bs[row * 40 + c4];
      db[0] = (__bf16)vb.x; db[1] = (__bf16)vb.y; db[2] = (__bf16)vb.z; db[3] = (__bf16)vb.w;
    }
    __syncthreads();
    bf16x8 af[4], bfr[4];
    #pragma unroll
    for (int i = 0; i < 4; i++)
      af[i] = *(const bf16x8*)&As[(wrow + i * 16 + l16) * 40 + quad * 8];
    #pragma unroll
    for (int j = 0; j < 4; j++)
      bfr[j] = *(const bf16x8*)&Bs[(wcol + j * 16 + l16) * 40 + quad * 8];
    #pragma unroll
    for (int i = 0; i < 4; i++)
      #pragma unroll
      for (int j = 0; j < 4; j++)
        acc[i][j] = __builtin_amdgcn_mfma_f32_16x16x32_bf16(af[i], bfr[j], acc[i][j], 0, 0, 0);
  }

  #pragma unroll
  for (int i = 0; i < 4; i++) {
    #pragma unroll
    for (int j = 0; j < 4; j++) {
      #pragma unroll
      for (int r = 0; r < 4; r++) {
        int m = m0 + wrow + i * 16 + quad * 4 + r;
        int n = n0 + wcol + j * 16 + l16;
        __bf16 v = (__bf16)acc[i][j][r];
        int b = m >> 11, s = m & (S_LEN - 1);
        if (sel == 0) {
          int h = n >> 7, d = n & 127;
          Qb[(((size_t)b * NH + h) * S_LEN + s) * HD + d] = v;
        } else if (sel == 1) {
          int nl = n - 4096, h = nl >> 7, d = nl & 127;
          Kb[(((size_t)b * NKV + h) * S_LEN + s) * HD + d] = v;
        } else {
          int nl = n - 5120, h = nl >> 7, d = nl & 127;
          Vt[(((size_t)b * NKV + h) * HD + d) * S_LEN + s] = v;
        }
      }
    }
  }
}

// ---------------------------------------------------------------------------
// FALLBACK OUT GEMM (fp32 Wo) — round-1 version.
// ---------------------------------------------------------------------------
__global__ __launch_bounds__(256) void out_gemm_f32(
    const __bf16* __restrict__ A, const float* __restrict__ Wo,
    float* __restrict__ C)
{
  __shared__ __bf16 As[128 * 40];
  __shared__ __bf16 Bs[128 * 40];
  const int tid  = threadIdx.x;
  const int wave = tid >> 6, lane = tid & 63;
  const int quad = lane >> 4, l16 = lane & 15;
  const int wrow = (wave >> 1) * 64, wcol = (wave & 1) * 64;
  const int m0 = blockIdx.y * 128;
  const int n0 = blockIdx.x * 128;

  floatx4 acc[4][4];
  #pragma unroll
  for (int i = 0; i < 4; i++)
    #pragma unroll
    for (int j = 0; j < 4; j++) acc[i][j] = (floatx4){0.f, 0.f, 0.f, 0.f};

  for (int k0 = 0; k0 < HIDN; k0 += 32) {
    __syncthreads();
    #pragma unroll
    for (int it = 0; it < 2; ++it) {
      int c = tid + it * 256;
      int row = c >> 2, c8 = (c & 3) * 8;
      *(bf16x8*)&As[row * 40 + c8] =
          *(const bf16x8*)(A + (size_t)(m0 + row) * HIDN + k0 + c8);
    }
    #pragma unroll
    for (int it = 0; it < 4; ++it) {
      int c = tid + it * 256;
      int row = c >> 3, c4 = (c & 7) * 4;
      float4 vb = *(const float4*)(Wo + (size_t)(n0 + row) * HIDN + k0 + c4);
      __bf16* db = &Bs[row * 40 + c4];
      db[0] = (__bf16)vb.x; db[1] = (__bf16)vb.y; db[2] = (__bf16)vb.z; db[3] = (__bf16)vb.w;
    }
    __syncthreads();
    bf16x8 af[4], bfr[4];
    #pragma unroll
    for (int i = 0; i < 4; i++)
      af[i] = *(const bf16x8*)&As[(wrow + i * 16 + l16) * 40 + quad * 8];
    #pragma unroll
    for (int j = 0; j < 4; j++)
      bfr[j] = *(const bf16x8*)&Bs[(wcol + j * 16 + l16) * 40 + quad * 8];
    #pragma unroll
    for (int i = 0; i < 4; i++)
      #pragma unroll
      for (int j = 0; j < 4; j++)
        acc[i][j] = __builtin_amdgcn_mfma_f32_16x16x32_bf16(af[i], bfr[j], acc[i][j], 0, 0, 0);
  }

  #pragma unroll
  for (int i = 0; i < 4; i++)
    #pragma unroll
    for (int j = 0; j < 4; j++)
      #pragma unroll
      for (int r = 0; r < 4; r++) {
        int m = m0 + wrow + i * 16 + quad * 4 + r;
        int n = n0 + wcol + j * 16 + l16;
        C[(size_t)m * HIDN + n] = acc[i][j][r];
      }
}

// ---------------------------------------------------------------------------
// RoPE in-place on bf16 Q and K.
// ---------------------------------------------------------------------------
__global__ __launch_bounds__(256) void rope_kernel(
    __bf16* __restrict__ Qb, __bf16* __restrict__ Kb,
    const float* __restrict__ cosp, const float* __restrict__ sinp)
{
  size_t i = (size_t)blockIdx.x * 256 + threadIdx.x;
  const size_t QP = (size_t)2 * NH * S_LEN * 64;
  __bf16* buf; int H; size_t t;
  if (i < QP) { buf = Qb; H = NH;  t = i; }
  else        { buf = Kb; H = NKV; t = i - QP; }
  int d = (int)(t & 63);
  int s = (int)((t >> 6) & (S_LEN - 1));
  size_t rest = t >> 17;
  int h = (int)(rest % H);
  int b = (int)(rest / H);
  size_t base = (((size_t)b * H + h) * S_LEN + s) * HD;
  float q0 = (float)buf[base + d];
  float q1 = (float)buf[base + d + 64];
  float c  = cosp[((size_t)b * S_LEN + s) * HD + d];
  float sn = sinp[((size_t)b * S_LEN + s) * HD + d];
  buf[base + d]      = (__bf16)(q0 * c - q1 * sn);
  buf[base + d + 64] = (__bf16)(q1 * c + q0 * sn);
}

// ---------------------------------------------------------------------------
// Flash attention, causal, GQA. Round 6: + s_setprio around MFMA clusters.
// ---------------------------------------------------------------------------
__global__ __launch_bounds__(256, 2) void flash_attn(
    const __bf16* __restrict__ Q, const __bf16* __restrict__ Kc,
    const __bf16* __restrict__ Vt, __bf16* __restrict__ Out)
{
  __shared__ __bf16 Ks[64 * 136];
  __shared__ __bf16 VTs[128 * 72];
  __shared__ __bf16 Ps[4 * 32 * 72];
  const int tid  = threadIdx.x;
  const int wave = tid >> 6, lane = tid & 63;
  const int quad = lane >> 4, l16 = lane & 15;
  const int bh = blockIdx.x;
  const int h = bh & 31, b = bh >> 5;
  const int qt = 15 - (int)blockIdx.y;   // longest first
  const int kvh = h >> 2;
  const size_t qbase  = (((size_t)b * NH + h) * S_LEN + qt * 128 + wave * 32) * HD;
  const size_t kbase  = ((size_t)b * NKV + kvh) * S_LEN * HD;
  const size_t vtbase = ((size_t)b * NKV + kvh) * (size_t)HD * S_LEN;
  const int psbase = wave * (32 * 72);

  bf16x8 qf[2][4];
  #pragma unroll
  for (int st = 0; st < 2; st++)
    #pragma unroll
    for (int kk = 0; kk < 4; kk++)
      qf[st][kk] = *(const bf16x8*)&Q[qbase + (size_t)(st * 16 + l16) * HD + kk * 32 + quad * 8];

  floatx4 o[2][8];
  floatx4 ol[2];
  #pragma unroll
  for (int st = 0; st < 2; st++) {
    ol[st] = (floatx4){0.f, 0.f, 0.f, 0.f};
    #pragma unroll
    for (int ct = 0; ct < 8; ct++) o[st][ct] = (floatx4){0.f, 0.f, 0.f, 0.f};
  }
  bf16x8 onesv;
  #pragma unroll
  for (int u = 0; u < 8; u++) onesv[u] = (__bf16)1.0f;

  const float c1 = 0.12753785f;   // scale * log2(e) = 128^-0.5 * 1.4426950
  const float c2 = -28.853900f;   // -20 * log2(e)
  const int kj_end = 2 * qt + 2;

  // prologue prefetch for kj = 0
  bf16x8 kreg[4], vreg[4];
  #pragma unroll
  for (int it = 0; it < 4; ++it) {
    int c = tid + it * 256;
    kreg[it] = *(const bf16x8*)&Kc[kbase + (size_t)((c >> 4)) * HD + (c & 15) * 8];
    vreg[it] = *(const bf16x8*)&Vt[vtbase + (size_t)(c >> 3) * S_LEN + (c & 7) * 8];
  }

  for (int kj = 0; kj < kj_end; ++kj) {
    __syncthreads();  // B1: prev iter's LDS reads done
    #pragma unroll
    for (int it = 0; it < 4; ++it) {
      int c = tid + it * 256;
      *(bf16x8*)&Ks[(c >> 4) * 136 + (c & 15) * 8] = kreg[it];
      *(bf16x8*)&VTs[(c >> 3) * 72 + (c & 7) * 8] = vreg[it];
    }
    __syncthreads();  // B2: staging visible

    // issue next-iter loads NOW — they fly under the whole compute phase
    if (kj + 1 < kj_end) {
      #pragma unroll
      for (int it = 0; it < 4; ++it) {
        int c = tid + it * 256;
        kreg[it] = *(const bf16x8*)&Kc[kbase + (size_t)((kj + 1) * 64 + (c >> 4)) * HD + (c & 15) * 8];
        vreg[it] = *(const bf16x8*)&Vt[vtbase + (size_t)(c >> 3) * S_LEN + (kj + 1) * 64 + (c & 7) * 8];
      }
    }

    // scores, transposed: S^T[kv][q]; A = K rows, B = Q rows.
    floatx4 s[2][4];
    #pragma unroll
    for (int st = 0; st < 2; st++)
      #pragma unroll
      for (int j = 0; j < 4; j++) s[st][j] = (floatx4){0.f, 0.f, 0.f, 0.f};
    #pragma unroll
    for (int kk = 0; kk < 4; kk++) {
      bf16x8 ak[4];
      #pragma unroll
      for (int j = 0; j < 4; j++)
        ak[j] = *(const bf16x8*)&Ks[(j * 16 + l16) * 136 + kk * 32 + quad * 8];
      __builtin_amdgcn_s_setprio(1);
      #pragma unroll
      for (int st = 0; st < 2; st++)
        #pragma unroll
        for (int j = 0; j < 4; j++)
          s[st][j] = __builtin_amdgcn_mfma_f32_16x16x32_bf16(ak[j], qf[st][kk], s[st][j], 0, 0, 0);
      __builtin_amdgcn_s_setprio(0);
    }

    // p = exp2(s*c1 + c2), causal-masked to 0; write per-wave Ps (no barrier).
    #pragma unroll
    for (int st = 0; st < 2; st++) {
      const int qrow = qt * 128 + wave * 32 + st * 16 + l16;
      #pragma unroll
      for (int j = 0; j < 4; j++) {
        const int kvb = kj * 64 + j * 16 + quad * 4;
        bf16x4 pw;
        #pragma unroll
        for (int r = 0; r < 4; r++) {
          float p = __builtin_amdgcn_exp2f(fmaf(s[st][j][r], c1, c2));
          if (kvb + r > qrow) p = 0.0f;
          pw[r] = (__bf16)p;
        }
        *(bf16x4*)&Ps[psbase + (st * 16 + l16) * 72 + j * 16 + quad * 4] = pw;
      }
    }

    // PV + row-sum l: O(32x128) += P(32x64) * V(64x128); l += P * ones
    #pragma unroll
    for (int kk = 0; kk < 2; kk++) {
      bf16x8 bv[8];
      #pragma unroll
      for (int ct = 0; ct < 8; ct++)
        bv[ct] = *(const bf16x8*)&VTs[(ct * 16 + l16) * 72 + kk * 32 + quad * 8];
      bf16x8 ap[2];
      #pragma unroll
      for (int st = 0; st < 2; st++)
        ap[st] = *(const bf16x8*)&Ps[psbase + (st * 16 + l16) * 72 + kk * 32 + quad * 8];
      __builtin_amdgcn_s_setprio(1);
      #pragma unroll
      for (int st = 0; st < 2; st++) {
        ol[st] = __builtin_amdgcn_mfma_f32_16x16x32_bf16(ap[st], onesv, ol[st], 0, 0, 0);
        #pragma unroll
        for (int ct = 0; ct < 8; ct++)
          o[st][ct] = __builtin_amdgcn_mfma_f32_16x16x32_bf16(ap[st], bv[ct], o[st][ct], 0, 0, 0);
      }
      __builtin_amdgcn_s_setprio(0);
    }
  }

  // epilogue: attn_out[b][s][h*128+d]; l = ol[st][r] (all cols identical)
  #pragma unroll
  for (int st = 0; st < 2; st++) {
    #pragma unroll
    for (int r = 0; r < 4; r++) {
      float rl = 1.0f / ol[st][r];
      int qi = qt * 128 + wave * 32 + st * 16 + quad * 4 + r;
      #pragma unroll
      for (int ct = 0; ct < 8; ct++) {
        Out[((size_t)b * S_LEN + qi) * HIDN + h * HD + ct * 16 + l16] =
            (__bf16)(o[st][ct][r] * rl);
      }
    }
  }
}

// ---------------------------------------------------------------------------
extern "C" void kernel_launch(void* const* d_in, const int* in_sizes, int n_in,
                              void* d_out, int out_size, void* d_ws, size_t ws_size,
                              hipStream_t stream)
{
  const float* hs   = (const float*)d_in[0];
  const float* cosp = (const float*)d_in[1];
  const float* sinp = (const float*)d_in[2];
  // d_in[3] = attention_mask: exactly causal -1e9, applied analytically in flash_attn
  const float* Wq   = (const float*)d_in[4];
  const float* Wk   = (const float*)d_in[5];
  const float* Wv   = (const float*)d_in[6];
  const float* Wo   = (const float*)d_in[7];
  float* out = (float*)d_out;

  __bf16* Qb  = (__bf16*)d_ws;                         // 16,777,216
  __bf16* Kb  = Qb  + (size_t)16777216;                //  4,194,304
  __bf16* Vtb = Kb  + (size_t)4194304;                 //  4,194,304

  if (ws_size >= (size_t)134217728) {
    __bf16* HSB = Vtb + (size_t)4194304;   // hs bf16; aliased by AO after qkv
    __bf16* AO  = HSB;
    __bf16* WB  = HSB + (size_t)16777216;  // Wq|Wk|Wv bf16; Wo aliases after qkv

    cvt_bf16<<<8192, 256, 0, stream>>>(hs, HSB, 2097152);
    cvt_bf16<<<8192, 256, 0, stream>>>(Wq, WB, 2097152);
    cvt_bf16<<<2048, 256, 0, stream>>>(Wk, WB + 16777216, 524288);
    cvt_bf16<<<2048, 256, 0, stream>>>(Wv, WB + 20971520, 524288);
    qkv_gemm_bf16<<<dim3(24, 32), 512, 0, stream>>>(HSB, WB, Qb, Kb, Vtb);
    cvt_bf16<<<8192, 256, 0, stream>>>(Wo, WB, 2097152);  // Wqkv dead now
    rope_kernel<<<40960, 256, 0, stream>>>(Qb, Kb, cosp, sinp);
    flash_attn<<<dim3(64, 16), 256, 0, stream>>>(Qb, Kb, Vtb, AO);
    out_gemm_bf16<<<dim3(16, 32), 512, 0, stream>>>(AO, WB, out);
  } else {
    __bf16* AO = Vtb + (size_t)4194304;
    qkv_gemm_f32<<<dim3(48, 32), 256, 0, stream>>>(hs, Wq, Wk, Wv, Qb, Kb, Vtb);
    rope_kernel<<<40960, 256, 0, stream>>>(Qb, Kb, cosp, sinp);
    flash_attn<<<dim3(64, 16), 256, 0, stream>>>(Qb, Kb, Vtb, AO);
    out_gemm_f32<<<dim3(32, 32), 256, 0, stream>>>(AO, Wo, out);
  }
}